// Round 17
// baseline (4998.341 us; speedup 1.0000x reference)
//
#include <hip/hip_runtime.h>
#include <hip/hip_bf16.h>

typedef _Float16 f16;
typedef _Float16 f16x8 __attribute__((ext_vector_type(8)));
typedef float f32x4 __attribute__((ext_vector_type(4)));

#define T_ 256
#define SC 2048.0f
#define INV_SC (1.0f / 2048.0f)
#define RMASK 15          // 16-slot rings for recurrent h buffers
#define NSTAGE 258        // L1 runs at skew 2
#define MFMA(A, B, C)  __builtin_amdgcn_mfma_f32_16x16x32_f16(A, B, C, 0, 0, 0)

// ---------------------------------------------------------------------------
// Numerics = round 8/14/16 EXACT: f16-hi GEMM + f16 a_lo + f16 W_lo
// compensation, fp32 cell state in registers. Base = round 16.
// CHANGE (r17): launch_bounds(1024) w/o min-occupancy (VGPR 64 -> up to 128)
// + group-of-4 load batching in both GEMM segments so ~4 iterations of
// A/Wlo loads are in flight per wave (was ~2 at 64 VGPR). MFMA order per
// accumulator unchanged -> bit-identical results to r16.
//   A-buffers (x or h frags): [mt 4][ks 32][part 2][lane 64][e 8] f16
//   W pack per layer: [which 2 (hi/lo*SC)][jb 128][nt 2][ks 64][lane 64][e 8]
// Sync: wave-0 poll -> goLds; two redf barriers; epilogue-only drain + LDS
// ctr flag publication (r16).
// ---------------------------------------------------------------------------

__global__ void prepack_x_kernel(const float* __restrict__ x, f16* __restrict__ X0) {
  unsigned int idx = blockIdx.x * 256 + threadIdx.x;  // < 33,554,432
  int e    = idx & 7;
  int l    = (idx >> 3) & 63;
  int part = (idx >> 9) & 1;
  int ks   = (idx >> 10) & 31;
  int mt   = (idx >> 15) & 3;
  int t    = idx >> 17;
  int m = mt * 16 + (l & 15);
  int k = ks * 32 + ((l >> 4) << 3) + e;
  int cc = k >> 9, kw = k & 511;
  float v = x[(((size_t)m * T_ + t) * 512 + kw) * 2 + cc];
  f16 h = (f16)v;
  X0[idx] = part ? (f16)((v - (float)h) * SC) : h;
}

// 16,777,216 threads exactly (grid 65536 x 256): hi plane + lo plane (both f16).
__global__ void prepack_w_kernel(const float* __restrict__ Wri, const float* __restrict__ Wii,
                                 const float* __restrict__ Wrh, const float* __restrict__ Wih,
                                 f16* __restrict__ out) {
  unsigned int idx = blockIdx.x * 256 + threadIdx.x;  // < 16,777,216
  int e     = idx & 7;
  int l     = (idx >> 3) & 63;
  int ks    = (idx >> 9) & 63;
  int nt    = (idx >> 15) & 1;
  int jb    = (idx >> 16) & 127;
  int which = idx >> 23;
  int n_local = nt * 16 + (l & 15);
  int np = jb * 32 + n_local;
  int j  = np >> 3;
  int g  = (np >> 1) & 3;
  int cc = np & 1;
  int k  = ks * 32 + ((l >> 4) << 3) + e;
  int kb = k >> 9, kw = k & 511;
  size_t s = (size_t)(g * 512 + j) * 512 + kw;
  float v;
  if (cc == 0) v = (kb == 0) ? Wri[s] : (kb == 1) ? -Wii[s] : (kb == 2) ? Wrh[s] : -Wih[s];
  else         v = (kb == 0) ? Wii[s] : (kb == 1) ?  Wri[s] : (kb == 2) ? Wih[s] :  Wrh[s];
  f16 h = (f16)v;
  out[idx] = which ? (f16)((v - (float)h) * SC) : h;
}

struct PersistArgs {
  const f16* X0;      // [T][131072] layer-0 x frags
  f16* ys0;           // 16-slot ring: layer-0 h frags (= layer-1 x input)
  f16* h1;            // 16-slot ring: layer-1 h frags
  const f16* Wpk0;    // [2][128][65536] (hi | lo)
  const f16* Wpk1;
  const float *br10, *bi10, *br20, *bi20;
  const float *br11, *bi11, *br21, *bi21;
  float* y;           // (B,T,512,2)
  float* hout;        // (2,B,512,2)
  float* cout;        // (2,B,512,2)
  unsigned* flags;    // [256]
};

// x-half partial GEMM over ks [ks0, ks0+cnt): Whi from LDS, Wlo from global.
// Group-of-4 load batching; MFMA order per accumulator = ascending i (as r16).
__device__ __forceinline__ void xgemm_part(const f16* __restrict__ Ab,
                                           const f16* __restrict__ WhiL,
                                           const f16* __restrict__ WloG,
                                           int mt, int ks0, int cnt, int l,
                                           f32x4& xm0, f32x4& xs0,
                                           f32x4& xm1, f32x4& xs1) {
  const f16* pa = Ab + mt * 32768 + ks0 * 1024 + l * 8;
  const f16* pw = WhiL + ks0 * 512 + l * 8;
  const f16* po = WloG + ks0 * 512 + l * 8;
  int i = 0;
  for (; i + 4 <= cnt; i += 4) {
    f16x8 ah[4], al4[4], o0[4], o1[4];
#pragma unroll
    for (int u = 0; u < 4; ++u) {
      int ii = i + u;
      ah[u]  = *reinterpret_cast<const f16x8*>(pa + ii * 1024);
      al4[u] = *reinterpret_cast<const f16x8*>(pa + ii * 1024 + 512);
      o0[u]  = *reinterpret_cast<const f16x8*>(po + ii * 512);
      o1[u]  = *reinterpret_cast<const f16x8*>(po + 32768 + ii * 512);
    }
#pragma unroll
    for (int u = 0; u < 4; ++u) {
      int ii = i + u;
      f16x8 w0 = *reinterpret_cast<const f16x8*>(pw + ii * 512);
      f16x8 w1 = *reinterpret_cast<const f16x8*>(pw + 32768 + ii * 512);
      xm0 = MFMA(ah[u], w0, xm0); xs0 = MFMA(al4[u], w0, xs0); xs0 = MFMA(ah[u], o0[u], xs0);
      xm1 = MFMA(ah[u], w1, xm1); xs1 = MFMA(al4[u], w1, xs1); xs1 = MFMA(ah[u], o1[u], xs1);
    }
  }
  for (; i < cnt; ++i) {
    f16x8 ah = *reinterpret_cast<const f16x8*>(pa + i * 1024);
    f16x8 al = *reinterpret_cast<const f16x8*>(pa + i * 1024 + 512);
    f16x8 w0 = *reinterpret_cast<const f16x8*>(pw + i * 512);
    f16x8 w1 = *reinterpret_cast<const f16x8*>(pw + 32768 + i * 512);
    f16x8 o0 = *reinterpret_cast<const f16x8*>(po + i * 512);
    f16x8 o1 = *reinterpret_cast<const f16x8*>(po + 32768 + i * 512);
    xm0 = MFMA(ah, w0, xm0); xs0 = MFMA(al, w0, xs0); xs0 = MFMA(ah, o0, xs0);
    xm1 = MFMA(ah, w1, xm1); xs1 = MFMA(al, w1, xs1); xs1 = MFMA(ah, o1, xs1);
  }
}

// 256 blocks x 1024 threads; stage s: L0 computes step s, L1 computes s-2.
__global__ __launch_bounds__(1024) void lstm_persist(PersistArgs a) {
  extern __shared__ char smem[];
  f16* Wl = (f16*)smem;                                  // W-hi full 131072 B
  float* redf = (float*)(smem + 131072);                 // [2][4][2][16][17] f32
  volatile unsigned* goLds = (volatile unsigned*)(smem + 148480);
  unsigned* ectr = (unsigned*)(smem + 148484);           // epilogue drain counter

  int bid = blockIdx.x;
  int xcd = bid & 7, rr = bid >> 3;
  int lay = rr & 1;
  int jb = (rr >> 1) * 8 + xcd;       // 0..127
  int tid = threadIdx.x;
  int w = tid >> 6, l = tid & 63;
  int mt = w & 3, kq = w >> 2;
  int n_loc = l & 15, r0 = (l >> 4) * 4;
  bool carrier = (kq >= 1);
  int xks0 = (kq == 1) ? 0 : (kq == 2) ? 11 : 22;   // x-half ks ranges 11/11/10
  int xcnt = (kq == 3) ? 10 : 11;

  // epilogue identity (tid < 256): one (m, j-local) pair
  int em = tid >> 2, ejl = tid & 3;
  int emt = em >> 4, eml = em & 15;
  int jg = jb * 4 + ejl;

  const f16* Wpk = lay ? a.Wpk1 : a.Wpk0;
  const f16* WhiG = Wpk + (size_t)jb * 65536;
  const f16* WloG = Wpk + 8388608 + (size_t)jb * 65536;
  for (int i = tid * 8; i < 65536; i += 8192)
    *reinterpret_cast<f16x8*>(Wl + i) = *reinterpret_cast<const f16x8*>(WhiG + i);
  if (tid == 0) { *goLds = 0u; *ectr = 0u; }

  float bsr[4], bsi[4];
  {
    const float* br1 = lay ? a.br11 : a.br10;
    const float* bi1 = lay ? a.bi11 : a.bi10;
    const float* br2 = lay ? a.br21 : a.br20;
    const float* bi2 = lay ? a.bi21 : a.bi20;
#pragma unroll
    for (int g = 0; g < 4; ++g) {
      int nb = g * 512 + jg;
      bsr[g] = br1[nb] + br2[nb];
      bsi[g] = bi1[nb] + bi2[nb];
    }
  }
  __syncthreads();

  const f32x4 z4 = {0.f, 0.f, 0.f, 0.f};
  f32x4 xm0 = z4, xs0 = z4, xm1 = z4, xs1 = z4;   // carried x-GEMM partials

  // prime: L0 carriers compute x-GEMM for t=0 (X0 static, no dependency)
  if (carrier && lay == 0)
    xgemm_part(a.X0, Wl, WloG, mt, xks0, xcnt, l, xm0, xs0, xm1, xs1);

  float c_r = 0.f, c_i = 0.f;

  for (int s = 0; s < NSTAGE; ++s) {
    bool active = lay ? (s >= 2) : (s < T_);
    int t = lay ? (s - 2) : s;

    if (s > 0) {   // wait: all blocks published stage s-1
      if (w == 0) {
        const unsigned* fp = a.flags + l * 4;
        for (;;) {
          unsigned f0 = __hip_atomic_load(fp + 0, __ATOMIC_RELAXED, __HIP_MEMORY_SCOPE_AGENT);
          unsigned f1 = __hip_atomic_load(fp + 1, __ATOMIC_RELAXED, __HIP_MEMORY_SCOPE_AGENT);
          unsigned f2 = __hip_atomic_load(fp + 2, __ATOMIC_RELAXED, __HIP_MEMORY_SCOPE_AGENT);
          unsigned f3 = __hip_atomic_load(fp + 3, __ATOMIC_RELAXED, __HIP_MEMORY_SCOPE_AGENT);
          unsigned mn = min(min(f0, f1), min(f2, f3));
          if (__all(mn >= (unsigned)s)) break;
          __builtin_amdgcn_s_sleep(1);
        }
        if (l == 0) { asm volatile("" ::: "memory"); *goLds = (unsigned)s; }
      } else {
        while (*goLds < (unsigned)s) __builtin_amdgcn_s_sleep(1);
      }
      asm volatile("" ::: "memory");
    }

    // ---- h-half GEMM (8 ks per wave, group-of-4 batched) + carried x ----
    f32x4 comb0 = z4, comb1 = z4;
    int rb0 = 0, rb1 = 0;
    if (active) {
      f32x4 acc0  = carrier ? xm0 : z4;
      f32x4 sacc0 = carrier ? xs0 : z4;
      f32x4 acc1  = carrier ? xm1 : z4;
      f32x4 sacc1 = carrier ? xs1 : z4;
      if (t > 0) {
        const f16* Ab = (lay ? a.h1 : a.ys0) + (size_t)((t - 1) & RMASK) * 131072;
        int ksl = kq * 8;              // h-buffer local ks
        int ksg = 32 + kq * 8;         // W global ks
        const f16* pa = Ab + mt * 32768 + ksl * 1024 + l * 8;
        const f16* pw = Wl + ksg * 512 + l * 8;
        const f16* po = WloG + ksg * 512 + l * 8;
#pragma unroll
        for (int g2 = 0; g2 < 2; ++g2) {
          f16x8 ah[4], al4[4], o0[4], o1[4];
#pragma unroll
          for (int u = 0; u < 4; ++u) {
            int ii = g2 * 4 + u;
            ah[u]  = *reinterpret_cast<const f16x8*>(pa + ii * 1024);
            al4[u] = *reinterpret_cast<const f16x8*>(pa + ii * 1024 + 512);
            o0[u]  = *reinterpret_cast<const f16x8*>(po + ii * 512);
            o1[u]  = *reinterpret_cast<const f16x8*>(po + 32768 + ii * 512);
          }
#pragma unroll
          for (int u = 0; u < 4; ++u) {
            int ii = g2 * 4 + u;
            f16x8 w0 = *reinterpret_cast<const f16x8*>(pw + ii * 512);
            f16x8 w1 = *reinterpret_cast<const f16x8*>(pw + 32768 + ii * 512);
            acc0 = MFMA(ah[u], w0, acc0); sacc0 = MFMA(al4[u], w0, sacc0); sacc0 = MFMA(ah[u], o0[u], sacc0);
            acc1 = MFMA(ah[u], w1, acc1); sacc1 = MFMA(al4[u], w1, sacc1); sacc1 = MFMA(ah[u], o1[u], sacc1);
          }
        }
      }
      comb0 = acc0 + sacc0 * INV_SC;
      comb1 = acc1 + sacc1 * INV_SC;
      rb0 = (((kq >> 1) * 4 + mt) * 2 + 0) * 272 + n_loc * 17 + r0;
      rb1 = (((kq >> 1) * 4 + mt) * 2 + 1) * 272 + n_loc * 17 + r0;
      if ((kq & 1) == 0) {
#pragma unroll
        for (int q = 0; q < 4; ++q) { redf[rb0 + q] = comb0[q]; redf[rb1 + q] = comb1[q]; }
      }
    }
    __syncthreads();
    if (active && (kq & 1)) {
#pragma unroll
      for (int q = 0; q < 4; ++q) { redf[rb0 + q] += comb0[q]; redf[rb1 + q] += comb1[q]; }
    }
    __syncthreads();

    if (kq == 0) {
      // ---------------- epilogue + drain + ctr-flag (kq0 waves only) ---------
      float hr = 0.f, him = 0.f, cnr = 0.f, cni = 0.f;
      if (active) {
        float zr[4], zi[4];
#pragma unroll
        for (int g = 0; g < 4; ++g) {
          int nl = ejl * 8 + g * 2;
          int nt_ = nl >> 4, nn = nl & 15;
          int i0 = (emt * 2 + nt_) * 272 + nn * 17 + eml;
          int i1 = ((4 + emt) * 2 + nt_) * 272 + nn * 17 + eml;
          zr[g] = redf[i0] + redf[i1] + bsr[g];
          zi[g] = redf[i0 + 17] + redf[i1 + 17] + bsi[g];
        }
        float gr[4], gi[4];
#pragma unroll
        for (int g = 0; g < 4; ++g) {
          float mag = sqrtf(zr[g] * zr[g] + zi[g] * zi[g]);
          float fn = (g < 3) ? (1.f / (1.f + __expf(-mag))) : tanhf(mag);
          float sg = fn / (mag + 1e-8f);
          gr[g] = zr[g] * sg;
          gi[g] = zi[g] * sg;
        }
        cnr = c_r * gr[1] + gr[0] * gr[3];
        cni = c_i * gi[1] + gi[0] * gi[3];
        c_r = cnr; c_i = cni;
        float mm = sqrtf(cnr * cnr + cni * cni);
        float sg = tanhf(mm) / (mm + 1e-8f);
        float dr = cnr * sg, di = cni * sg;
        hr  = gr[2] * dr - gi[2] * di;
        him = gi[2] * dr + gr[2] * di;

        // f16 h-frags pairwise (j, j^1): 2 u32 MALL stores per lane
        f16 h0 = (f16)hr, h2 = (f16)him;
        unsigned a1 = (unsigned)__builtin_bit_cast(unsigned short, h0)
                    | ((unsigned)__builtin_bit_cast(unsigned short, (f16)((hr - (float)h0) * SC)) << 16);
        unsigned a2 = (unsigned)__builtin_bit_cast(unsigned short, h2)
                    | ((unsigned)__builtin_bit_cast(unsigned short, (f16)((him - (float)h2) * SC)) << 16);
        unsigned b1 = __shfl_xor(a1, 1, 64);
        unsigned b2 = __shfl_xor(a2, 1, 64);
        unsigned v0, v1; int kbase;
        int p = ejl >> 1;
        if ((ejl & 1) == 0) {
          v0 = (a1 & 0xffffu) | (b1 << 16);
          v1 = (a1 >> 16) | (b1 & 0xffff0000u);
          kbase = jb * 4 + 2 * p;               // real planes
        } else {
          v0 = (b2 & 0xffffu) | (a2 << 16);
          v1 = (b2 >> 16) | (a2 & 0xffff0000u);
          kbase = 512 + jb * 4 + 2 * p;         // imag planes
        }
        f16* Yb = (lay ? a.h1 : a.ys0) + (size_t)(t & RMASK) * 131072;
        unsigned* Y32 = (unsigned*)Yb;
        int ks2 = kbase >> 5;
        int lane_h = eml + 16 * ((kbase >> 3) & 3);
        int e0 = kbase & 7;
        int idx0 = ((emt * 32 + ks2) * 2 + 0) * 512 + lane_h * 8 + e0;
        int idx1 = ((emt * 32 + ks2) * 2 + 1) * 512 + lane_h * 8 + e0;
        __hip_atomic_store(&Y32[idx0 >> 1], v0, __ATOMIC_RELAXED, __HIP_MEMORY_SCOPE_AGENT);
        __hip_atomic_store(&Y32[idx1 >> 1], v1, __ATOMIC_RELAXED, __HIP_MEMORY_SCOPE_AGENT);
      }
      asm volatile("s_waitcnt vmcnt(0)" ::: "memory");  // this wave's h-stores ack'd
      if (l == 0) {
        unsigned old = __hip_atomic_fetch_add(ectr, 1u, __ATOMIC_ACQ_REL,
                                              __HIP_MEMORY_SCOPE_WORKGROUP);
        if ((old & 3u) == 3u && s + 1 < NSTAGE)
          __hip_atomic_store(&a.flags[bid], (unsigned)(s + 1),
                             __ATOMIC_RELAXED, __HIP_MEMORY_SCOPE_AGENT);
      }
      // deferred fp32 outputs — off the flag path
      if (active) {
        if (lay) {
          float2 yv; yv.x = hr; yv.y = him;
          *reinterpret_cast<float2*>(a.y + (((size_t)em * T_ + t) * 512 + jg) * 2) = yv;
        }
        if (t == T_ - 1) {
          float* hp = a.hout + (size_t)lay * 65536 + ((size_t)em * 512 + jg) * 2;
          hp[0] = hr; hp[1] = him;
          float* cq = a.cout + (size_t)lay * 65536 + ((size_t)em * 512 + jg) * 2;
          cq[0] = cnr; cq[1] = cni;
        }
      }
    } else {
      // ---- carrier x-GEMM for stage s+1 (overlaps epilogue/drain/flag) ----
      xm0 = z4; xs0 = z4; xm1 = z4; xs1 = z4;
      bool nextAct = lay ? (s + 1 >= 2 && s + 1 < NSTAGE) : (s + 1 < T_);
      if (nextAct) {
        int tn = lay ? (s - 1) : (s + 1);   // next stage's step
        const f16* Ab = lay ? (a.ys0 + (size_t)(tn & RMASK) * 131072)
                            : (a.X0 + (size_t)tn * 131072);
        xgemm_part(Ab, Wl, WloG, mt, xks0, xcnt, l, xm0, xs0, xm1, xs1);
      }
    }
  }
}

extern "C" void kernel_launch(void* const* d_in, const int* in_sizes, int n_in,
                              void* d_out, int out_size, void* d_ws, size_t ws_size,
                              hipStream_t stream) {
  const float* x = (const float*)d_in[0];
  char* ws = (char*)d_ws;
  f16* X0   = (f16*)(ws + 0);                          //  64 MB
  f16* Wpk0 = (f16*)(ws + (size_t)67108864);           //  32 MB (hi|lo)
  f16* Wpk1 = (f16*)(ws + (size_t)100663296);          //  32 MB
  f16* ys0  = (f16*)(ws + (size_t)134217728);          //   4 MB ring
  f16* h1   = (f16*)(ws + (size_t)138412032);          //   4 MB ring
  unsigned* flags = (unsigned*)(ws + (size_t)142606336);  // 1 KB

  hipMemsetAsync(ws + 142606336, 0, 1024, stream);

  prepack_x_kernel<<<131072, 256, 0, stream>>>(x, X0);
  prepack_w_kernel<<<65536, 256, 0, stream>>>((const float*)d_in[1], (const float*)d_in[2],
                                              (const float*)d_in[5], (const float*)d_in[6], Wpk0);
  prepack_w_kernel<<<65536, 256, 0, stream>>>((const float*)d_in[9], (const float*)d_in[10],
                                              (const float*)d_in[13], (const float*)d_in[14], Wpk1);

  float* y = (float*)d_out;
  PersistArgs pa;
  pa.X0 = X0; pa.ys0 = ys0; pa.h1 = h1;
  pa.Wpk0 = Wpk0; pa.Wpk1 = Wpk1;
  pa.br10 = (const float*)d_in[3];  pa.bi10 = (const float*)d_in[4];
  pa.br20 = (const float*)d_in[7];  pa.bi20 = (const float*)d_in[8];
  pa.br11 = (const float*)d_in[11]; pa.bi11 = (const float*)d_in[12];
  pa.br21 = (const float*)d_in[15]; pa.bi21 = (const float*)d_in[16];
  pa.y = y; pa.hout = y + 16777216; pa.cout = y + 16777216 + 131072;
  pa.flags = flags;

  hipFuncSetAttribute((const void*)lstm_persist,
                      hipFuncAttributeMaxDynamicSharedMemorySize, 148608);
  void* kargs[] = { &pa };
  hipLaunchCooperativeKernel((const void*)lstm_persist, dim3(256), dim3(1024),
                             kargs, 148608, stream);
}

// Round 19
// 3985.121 us; speedup vs baseline: 1.2543x; 1.2543x over previous
//
#include <hip/hip_runtime.h>
#include <hip/hip_bf16.h>

typedef _Float16 f16;
typedef _Float16 f16x8 __attribute__((ext_vector_type(8)));
typedef float f32x4 __attribute__((ext_vector_type(4)));

#define T_ 256
#define SC 2048.0f
#define INV_SC (1.0f / 2048.0f)
#define RMASK 15          // 16-slot rings for recurrent h buffers
#define NSTAGE 258        // L1 runs at skew 2
#define MFMA(A, B, C)  __builtin_amdgcn_mfma_f32_16x16x32_f16(A, B, C, 0, 0, 0)

// ---------------------------------------------------------------------------
// ROUND 19 = ROUND 14 VERBATIM (fastest proven: 3.98 ms, absmax 0.0039).
// Numerics = round 8 EXACT: f16-hi GEMM + f16 a_lo + f16 W_lo compensation,
// fp32 cell state in registers. BOTH residual terms are required (r9: dropping
// W_lo -> 0.114; r18: dropping a_lo on h-path -> 0.186).
// Dataflow: x-half GEMM carried in registers (prefetched for stage s+1 by
// waves kq>=2 after flag publication; L1 at skew-2); h-half split across all
// 16 waves (8 ks each).
// Sync = round 11 proven skeleton: wave-0 poll -> goLds, two redf barriers,
// block-wide vmcnt(0) + __syncthreads + tid0 flag.
//   A-buffers (x or h frags): [mt 4][ks 32][part 2][lane 64][e 8] f16
//   W pack per layer: [which 2 (hi/lo*SC)][jb 128][nt 2][ks 64][lane 64][e 8]
// ---------------------------------------------------------------------------

__global__ void prepack_x_kernel(const float* __restrict__ x, f16* __restrict__ X0) {
  unsigned int idx = blockIdx.x * 256 + threadIdx.x;  // < 33,554,432
  int e    = idx & 7;
  int l    = (idx >> 3) & 63;
  int part = (idx >> 9) & 1;
  int ks   = (idx >> 10) & 31;
  int mt   = (idx >> 15) & 3;
  int t    = idx >> 17;
  int m = mt * 16 + (l & 15);
  int k = ks * 32 + ((l >> 4) << 3) + e;
  int cc = k >> 9, kw = k & 511;
  float v = x[(((size_t)m * T_ + t) * 512 + kw) * 2 + cc];
  f16 h = (f16)v;
  X0[idx] = part ? (f16)((v - (float)h) * SC) : h;
}

// 16,777,216 threads exactly (grid 65536 x 256): hi plane + lo plane (both f16).
__global__ void prepack_w_kernel(const float* __restrict__ Wri, const float* __restrict__ Wii,
                                 const float* __restrict__ Wrh, const float* __restrict__ Wih,
                                 f16* __restrict__ out) {
  unsigned int idx = blockIdx.x * 256 + threadIdx.x;  // < 16,777,216
  int e     = idx & 7;
  int l     = (idx >> 3) & 63;
  int ks    = (idx >> 9) & 63;
  int nt    = (idx >> 15) & 1;
  int jb    = (idx >> 16) & 127;
  int which = idx >> 23;
  int n_local = nt * 16 + (l & 15);
  int np = jb * 32 + n_local;
  int j  = np >> 3;
  int g  = (np >> 1) & 3;
  int cc = np & 1;
  int k  = ks * 32 + ((l >> 4) << 3) + e;
  int kb = k >> 9, kw = k & 511;
  size_t s = (size_t)(g * 512 + j) * 512 + kw;
  float v;
  if (cc == 0) v = (kb == 0) ? Wri[s] : (kb == 1) ? -Wii[s] : (kb == 2) ? Wrh[s] : -Wih[s];
  else         v = (kb == 0) ? Wii[s] : (kb == 1) ?  Wri[s] : (kb == 2) ? Wih[s] :  Wrh[s];
  f16 h = (f16)v;
  out[idx] = which ? (f16)((v - (float)h) * SC) : h;
}

struct PersistArgs {
  const f16* X0;      // [T][131072] layer-0 x frags
  f16* ys0;           // 16-slot ring: layer-0 h frags (= layer-1 x input)
  f16* h1;            // 16-slot ring: layer-1 h frags
  const f16* Wpk0;    // [2][128][65536] (hi | lo)
  const f16* Wpk1;
  const float *br10, *bi10, *br20, *bi20;
  const float *br11, *bi11, *br21, *bi21;
  float* y;           // (B,T,512,2)
  float* hout;        // (2,B,512,2)
  float* cout;        // (2,B,512,2)
  unsigned* flags;    // [256]
};

// 256 blocks x 1024 threads; stage s: L0 computes step s, L1 computes s-2.
__global__ __launch_bounds__(1024, 4) void lstm_persist(PersistArgs a) {
  extern __shared__ char smem[];
  f16* Wl = (f16*)smem;                                  // W-hi slice 131072 B
  float* redf = (float*)(smem + 131072);                 // [2][4][2][16][17] f32
  volatile unsigned* goLds = (volatile unsigned*)(smem + 148480);

  int bid = blockIdx.x;
  int xcd = bid & 7, rr = bid >> 3;
  int lay = rr & 1;
  int jb = (rr >> 1) * 8 + xcd;       // 0..127
  int tid = threadIdx.x;
  int w = tid >> 6, l = tid & 63;
  int mt = w & 3, kq = w >> 2;
  int n_loc = l & 15, r0 = (l >> 4) * 4;
  bool carrier = (kq >= 2);

  // epilogue identity (tid < 256): one (m, j-local) pair
  int em = tid >> 2, ejl = tid & 3;
  int emt = em >> 4, eml = em & 15;
  int jg = jb * 4 + ejl;

  const f16* Wpk = lay ? a.Wpk1 : a.Wpk0;
  const f16* WhiG = Wpk + (size_t)jb * 65536;
  const f16* WloG = Wpk + 8388608 + (size_t)jb * 65536;
  for (int i = tid * 8; i < 65536; i += 8192)
    *reinterpret_cast<f16x8*>(Wl + i) = *reinterpret_cast<const f16x8*>(WhiG + i);
  if (tid == 0) *goLds = 0u;

  float bsr[4], bsi[4];
  {
    const float* br1 = lay ? a.br11 : a.br10;
    const float* bi1 = lay ? a.bi11 : a.bi10;
    const float* br2 = lay ? a.br21 : a.br20;
    const float* bi2 = lay ? a.bi21 : a.bi20;
#pragma unroll
    for (int g = 0; g < 4; ++g) {
      int nb = g * 512 + jg;
      bsr[g] = br1[nb] + br2[nb];
      bsi[g] = bi1[nb] + bi2[nb];
    }
  }
  __syncthreads();

  const f32x4 z4 = {0.f, 0.f, 0.f, 0.f};
  f32x4 xm0 = z4, xs0 = z4, xm1 = z4, xs1 = z4;   // carried x-GEMM partials

  // prime: L0 carriers compute x-GEMM for t=0 (X0 static, no dependency)
  if (carrier && lay == 0) {
    int ksl = (kq - 2) * 16;
    const f16* pa = a.X0 + mt * 32768 + ksl * 1024 + l * 8;
    const f16* pw = Wl + ksl * 512 + l * 8;
    const f16* po = WloG + ksl * 512 + l * 8;
#pragma unroll 4
    for (int i = 0; i < 16; ++i) {
      f16x8 ah = *reinterpret_cast<const f16x8*>(pa + i * 1024);
      f16x8 al = *reinterpret_cast<const f16x8*>(pa + i * 1024 + 512);
      f16x8 w0 = *reinterpret_cast<const f16x8*>(pw + i * 512);
      f16x8 w1 = *reinterpret_cast<const f16x8*>(pw + 32768 + i * 512);
      f16x8 o0 = *reinterpret_cast<const f16x8*>(po + i * 512);
      f16x8 o1 = *reinterpret_cast<const f16x8*>(po + 32768 + i * 512);
      xm0 = MFMA(ah, w0, xm0); xs0 = MFMA(al, w0, xs0); xs0 = MFMA(ah, o0, xs0);
      xm1 = MFMA(ah, w1, xm1); xs1 = MFMA(al, w1, xs1); xs1 = MFMA(ah, o1, xs1);
    }
  }

  float c_r = 0.f, c_i = 0.f;

  for (int s = 0; s < NSTAGE; ++s) {
    bool active = lay ? (s >= 2) : (s < T_);
    int t = lay ? (s - 2) : s;

    if (s > 0) {   // wait: all blocks published stage s-1  (round-11 skeleton)
      if (w == 0) {
        const unsigned* fp = a.flags + l * 4;
        for (;;) {
          unsigned f0 = __hip_atomic_load(fp + 0, __ATOMIC_RELAXED, __HIP_MEMORY_SCOPE_AGENT);
          unsigned f1 = __hip_atomic_load(fp + 1, __ATOMIC_RELAXED, __HIP_MEMORY_SCOPE_AGENT);
          unsigned f2 = __hip_atomic_load(fp + 2, __ATOMIC_RELAXED, __HIP_MEMORY_SCOPE_AGENT);
          unsigned f3 = __hip_atomic_load(fp + 3, __ATOMIC_RELAXED, __HIP_MEMORY_SCOPE_AGENT);
          unsigned mn = min(min(f0, f1), min(f2, f3));
          if (__all(mn >= (unsigned)s)) break;
          __builtin_amdgcn_s_sleep(1);
        }
        if (l == 0) { asm volatile("" ::: "memory"); *goLds = (unsigned)s; }
      } else {
        while (*goLds < (unsigned)s) __builtin_amdgcn_s_sleep(1);
      }
      asm volatile("" ::: "memory");
    }

    // ---- h-half GEMM (8 ks per wave) on top of carried x partials ----
    f32x4 comb0 = z4, comb1 = z4;
    int rb0 = 0, rb1 = 0;
    if (active) {
      f32x4 acc0  = carrier ? xm0 : z4;
      f32x4 sacc0 = carrier ? xs0 : z4;
      f32x4 acc1  = carrier ? xm1 : z4;
      f32x4 sacc1 = carrier ? xs1 : z4;
      if (t > 0) {
        const f16* Ab = (lay ? a.h1 : a.ys0) + (size_t)((t - 1) & RMASK) * 131072;
        int ksl = kq * 8;              // h-buffer local ks
        int ksg = 32 + kq * 8;         // W global ks
        const f16* pa = Ab + mt * 32768 + ksl * 1024 + l * 8;
        const f16* pw = Wl + ksg * 512 + l * 8;
        const f16* po = WloG + ksg * 512 + l * 8;
#pragma unroll
        for (int i = 0; i < 8; ++i) {
          f16x8 ah = *reinterpret_cast<const f16x8*>(pa + i * 1024);
          f16x8 al = *reinterpret_cast<const f16x8*>(pa + i * 1024 + 512);
          f16x8 w0 = *reinterpret_cast<const f16x8*>(pw + i * 512);
          f16x8 w1 = *reinterpret_cast<const f16x8*>(pw + 32768 + i * 512);
          f16x8 o0 = *reinterpret_cast<const f16x8*>(po + i * 512);
          f16x8 o1 = *reinterpret_cast<const f16x8*>(po + 32768 + i * 512);
          acc0 = MFMA(ah, w0, acc0); sacc0 = MFMA(al, w0, sacc0); sacc0 = MFMA(ah, o0, sacc0);
          acc1 = MFMA(ah, w1, acc1); sacc1 = MFMA(al, w1, sacc1); sacc1 = MFMA(ah, o1, sacc1);
        }
      }
      comb0 = acc0 + sacc0 * INV_SC;
      comb1 = acc1 + sacc1 * INV_SC;
      rb0 = (((kq >> 1) * 4 + mt) * 2 + 0) * 272 + n_loc * 17 + r0;
      rb1 = (((kq >> 1) * 4 + mt) * 2 + 1) * 272 + n_loc * 17 + r0;
      if ((kq & 1) == 0) {
#pragma unroll
        for (int q = 0; q < 4; ++q) { redf[rb0 + q] = comb0[q]; redf[rb1 + q] = comb1[q]; }
      }
    }
    __syncthreads();
    if (active && (kq & 1)) {
#pragma unroll
      for (int q = 0; q < 4; ++q) { redf[rb0 + q] += comb0[q]; redf[rb1 + q] += comb1[q]; }
    }
    __syncthreads();

    float hr = 0.f, him = 0.f, cnr = 0.f, cni = 0.f;
    if (active && tid < 256) {
      float zr[4], zi[4];
#pragma unroll
      for (int g = 0; g < 4; ++g) {
        int nl = ejl * 8 + g * 2;
        int nt_ = nl >> 4, nn = nl & 15;
        int i0 = (emt * 2 + nt_) * 272 + nn * 17 + eml;
        int i1 = ((4 + emt) * 2 + nt_) * 272 + nn * 17 + eml;
        zr[g] = redf[i0] + redf[i1] + bsr[g];
        zi[g] = redf[i0 + 17] + redf[i1 + 17] + bsi[g];
      }
      float gr[4], gi[4];
#pragma unroll
      for (int g = 0; g < 4; ++g) {
        float mag = sqrtf(zr[g] * zr[g] + zi[g] * zi[g]);
        float fn = (g < 3) ? (1.f / (1.f + __expf(-mag))) : tanhf(mag);
        float sg = fn / (mag + 1e-8f);
        gr[g] = zr[g] * sg;
        gi[g] = zi[g] * sg;
      }
      cnr = c_r * gr[1] + gr[0] * gr[3];
      cni = c_i * gi[1] + gi[0] * gi[3];
      c_r = cnr; c_i = cni;
      float mm = sqrtf(cnr * cnr + cni * cni);
      float sg = tanhf(mm) / (mm + 1e-8f);
      float dr = cnr * sg, di = cni * sg;
      hr  = gr[2] * dr - gi[2] * di;
      him = gi[2] * dr + gr[2] * di;

      // f16 h-frags pairwise (j, j^1): 2 u32 MALL stores per lane
      f16 h0 = (f16)hr, h2 = (f16)him;
      unsigned a1 = (unsigned)__builtin_bit_cast(unsigned short, h0)
                  | ((unsigned)__builtin_bit_cast(unsigned short, (f16)((hr - (float)h0) * SC)) << 16);
      unsigned a2 = (unsigned)__builtin_bit_cast(unsigned short, h2)
                  | ((unsigned)__builtin_bit_cast(unsigned short, (f16)((him - (float)h2) * SC)) << 16);
      unsigned b1 = __shfl_xor(a1, 1, 64);
      unsigned b2 = __shfl_xor(a2, 1, 64);
      unsigned v0, v1; int kbase;
      int p = ejl >> 1;
      if ((ejl & 1) == 0) {
        v0 = (a1 & 0xffffu) | (b1 << 16);
        v1 = (a1 >> 16) | (b1 & 0xffff0000u);
        kbase = jb * 4 + 2 * p;               // real planes
      } else {
        v0 = (b2 & 0xffffu) | (a2 << 16);
        v1 = (b2 >> 16) | (a2 & 0xffff0000u);
        kbase = 512 + jb * 4 + 2 * p;         // imag planes
      }
      f16* Yb = (lay ? a.h1 : a.ys0) + (size_t)(t & RMASK) * 131072;
      unsigned* Y32 = (unsigned*)Yb;
      int ks2 = kbase >> 5;
      int lane_h = eml + 16 * ((kbase >> 3) & 3);
      int e0 = kbase & 7;
      int idx0 = ((emt * 32 + ks2) * 2 + 0) * 512 + lane_h * 8 + e0;
      int idx1 = ((emt * 32 + ks2) * 2 + 1) * 512 + lane_h * 8 + e0;
      __hip_atomic_store(&Y32[idx0 >> 1], v0, __ATOMIC_RELAXED, __HIP_MEMORY_SCOPE_AGENT);
      __hip_atomic_store(&Y32[idx1 >> 1], v1, __ATOMIC_RELAXED, __HIP_MEMORY_SCOPE_AGENT);
    }

    asm volatile("s_waitcnt vmcnt(0)" ::: "memory");   // drain h-stores (per-wave)
    __syncthreads();
    if (tid == 0 && s + 1 < NSTAGE)
      __hip_atomic_store(&a.flags[bid], (unsigned)(s + 1),
                         __ATOMIC_RELAXED, __HIP_MEMORY_SCOPE_AGENT);

    // ---- carrier x-prefetch for stage s+1 (overlaps inter-block poll) ----
    if (carrier) {
      xm0 = z4; xs0 = z4; xm1 = z4; xs1 = z4;
      bool nextAct = lay ? (s + 1 >= 2 && s + 1 < NSTAGE) : (s + 1 < T_);
      if (nextAct) {
        int tn = lay ? (s - 1) : (s + 1);   // next stage's step
        const f16* Ab = lay ? (a.ys0 + (size_t)(tn & RMASK) * 131072)
                            : (a.X0 + (size_t)tn * 131072);
        int ksl = (kq - 2) * 16;
        const f16* pa = Ab + mt * 32768 + ksl * 1024 + l * 8;
        const f16* pw = Wl + ksl * 512 + l * 8;
        const f16* po = WloG + ksl * 512 + l * 8;
#pragma unroll 4
        for (int i = 0; i < 16; ++i) {
          f16x8 ah = *reinterpret_cast<const f16x8*>(pa + i * 1024);
          f16x8 al = *reinterpret_cast<const f16x8*>(pa + i * 1024 + 512);
          f16x8 w0 = *reinterpret_cast<const f16x8*>(pw + i * 512);
          f16x8 w1 = *reinterpret_cast<const f16x8*>(pw + 32768 + i * 512);
          f16x8 o0 = *reinterpret_cast<const f16x8*>(po + i * 512);
          f16x8 o1 = *reinterpret_cast<const f16x8*>(po + 32768 + i * 512);
          xm0 = MFMA(ah, w0, xm0); xs0 = MFMA(al, w0, xs0); xs0 = MFMA(ah, o0, xs0);
          xm1 = MFMA(ah, w1, xm1); xs1 = MFMA(al, w1, xs1); xs1 = MFMA(ah, o1, xs1);
        }
      }
    }

    // deferred fp32 outputs — off the flag path
    if (active && tid < 256) {
      if (lay) {
        float2 yv; yv.x = hr; yv.y = him;
        *reinterpret_cast<float2*>(a.y + (((size_t)em * T_ + t) * 512 + jg) * 2) = yv;
      }
      if (t == T_ - 1) {
        float* hp = a.hout + (size_t)lay * 65536 + ((size_t)em * 512 + jg) * 2;
        hp[0] = hr; hp[1] = him;
        float* cq = a.cout + (size_t)lay * 65536 + ((size_t)em * 512 + jg) * 2;
        cq[0] = cnr; cq[1] = cni;
      }
    }
  }
}

extern "C" void kernel_launch(void* const* d_in, const int* in_sizes, int n_in,
                              void* d_out, int out_size, void* d_ws, size_t ws_size,
                              hipStream_t stream) {
  const float* x = (const float*)d_in[0];
  char* ws = (char*)d_ws;
  f16* X0   = (f16*)(ws + 0);                          //  64 MB
  f16* Wpk0 = (f16*)(ws + (size_t)67108864);           //  32 MB (hi|lo)
  f16* Wpk1 = (f16*)(ws + (size_t)100663296);          //  32 MB
  f16* ys0  = (f16*)(ws + (size_t)134217728);          //   4 MB ring
  f16* h1   = (f16*)(ws + (size_t)138412032);          //   4 MB ring
  unsigned* flags = (unsigned*)(ws + (size_t)142606336);  // 1 KB

  hipMemsetAsync(ws + 142606336, 0, 1024, stream);

  prepack_x_kernel<<<131072, 256, 0, stream>>>(x, X0);
  prepack_w_kernel<<<65536, 256, 0, stream>>>((const float*)d_in[1], (const float*)d_in[2],
                                              (const float*)d_in[5], (const float*)d_in[6], Wpk0);
  prepack_w_kernel<<<65536, 256, 0, stream>>>((const float*)d_in[9], (const float*)d_in[10],
                                              (const float*)d_in[13], (const float*)d_in[14], Wpk1);

  float* y = (float*)d_out;
  PersistArgs pa;
  pa.X0 = X0; pa.ys0 = ys0; pa.h1 = h1;
  pa.Wpk0 = Wpk0; pa.Wpk1 = Wpk1;
  pa.br10 = (const float*)d_in[3];  pa.bi10 = (const float*)d_in[4];
  pa.br20 = (const float*)d_in[7];  pa.bi20 = (const float*)d_in[8];
  pa.br11 = (const float*)d_in[11]; pa.bi11 = (const float*)d_in[12];
  pa.br21 = (const float*)d_in[15]; pa.bi21 = (const float*)d_in[16];
  pa.y = y; pa.hout = y + 16777216; pa.cout = y + 16777216 + 131072;
  pa.flags = flags;

  hipFuncSetAttribute((const void*)lstm_persist,
                      hipFuncAttributeMaxDynamicSharedMemorySize, 148608);
  void* kargs[] = { &pa };
  hipLaunchCooperativeKernel((const void*)lstm_persist, dim3(256), dim3(1024),
                             kargs, 148608, stream);
}